// Round 7
// baseline (411.875 us; speedup 1.0000x reference)
//
#include <hip/hip_runtime.h>

#define N_SRC   100000
#define N_DST   100000
#define N_EDGES 1250000
#define D_FEAT  64
#define HIDDEN  64
#define OUT_F   128

#define NB_SCAN 196   // ceil(N_DST / 512); each scan block owns 512 counts

// ---------------------------------------------------------------------------
// Kernel 1: hs = relu(h_src @ W1 + b1)   [N_SRC, 64]
// Wave per row (grid-stride). W1 column `lane` pinned in 64 VGPRs; x-row via
// scalar loads (uniform row) -> pure v_fmac with SGPR broadcast.
// ---------------------------------------------------------------------------
__global__ __launch_bounds__(256) void fc1_kernel(
        const float* __restrict__ h_src, const float* __restrict__ W1,
        const float* __restrict__ b1, float* __restrict__ hs) {
    const int lane = threadIdx.x & 63;
    float wcol[64];                            // W1[k][lane]
    #pragma unroll
    for (int k = 0; k < 64; ++k) wcol[k] = W1[k * HIDDEN + lane];
    #pragma unroll
    for (int k = 0; k < 64; ++k) asm volatile("" : "+v"(wcol[k]));
    const float bias = b1[lane];
    const int wid    = blockIdx.x * 4 + (threadIdx.x >> 6);
    const int stride = gridDim.x * 4;
    for (int row = wid; row < N_SRC; row += stride) {
        const int urow = __builtin_amdgcn_readfirstlane(row);
        const float* __restrict__ xr = h_src + (size_t)urow * 64;
        float a0 = bias, a1 = 0.f, a2 = 0.f, a3 = 0.f;
        #pragma unroll
        for (int k = 0; k < 64; k += 4) {
            a0 = fmaf(xr[k],     wcol[k],     a0);
            a1 = fmaf(xr[k + 1], wcol[k + 1], a1);
            a2 = fmaf(xr[k + 2], wcol[k + 2], a2);
            a3 = fmaf(xr[k + 3], wcol[k + 3], a3);
        }
        hs[(size_t)urow * 64 + lane] = fmaxf((a0 + a1) + (a2 + a3), 0.0f);
    }
}

// ---------------------------------------------------------------------------
// CSR build, step 1: histogram of dst.
// ---------------------------------------------------------------------------
__global__ __launch_bounds__(256) void hist_kernel(
        const int* __restrict__ dst, int* __restrict__ counts) {
    int i = blockIdx.x * blockDim.x + threadIdx.x;
    const int stride = gridDim.x * blockDim.x;
    for (; i < N_EDGES; i += stride) atomicAdd(&counts[dst[i]], 1);
}

// ---------------------------------------------------------------------------
// CSR scan phase A: per-block sums (196 blocks x 512 counts).
// ---------------------------------------------------------------------------
__global__ __launch_bounds__(256) void scan_bsum_kernel(
        const int* __restrict__ c, int* __restrict__ bsum) {
    const int t  = threadIdx.x;
    const int i0 = blockIdx.x * 512 + 2 * t;
    int v0 = (i0     < N_DST) ? c[i0]     : 0;
    int v1 = (i0 + 1 < N_DST) ? c[i0 + 1] : 0;
    int s = v0 + v1;
    #pragma unroll
    for (int off = 32; off > 0; off >>= 1) s += __shfl_down(s, off, 64);
    __shared__ int ws[4];
    if ((t & 63) == 0) ws[t >> 6] = s;
    __syncthreads();
    if (t == 0) bsum[blockIdx.x] = ws[0] + ws[1] + ws[2] + ws[3];
}

// ---------------------------------------------------------------------------
// CSR scan phase B: single small block — exclusive scan of the 196 sums.
// ---------------------------------------------------------------------------
__global__ __launch_bounds__(256) void scan_boff_kernel(
        const int* __restrict__ bsum, int* __restrict__ boff) {
    const int t = threadIdx.x, lane = t & 63, w = t >> 6;
    int v = (t < NB_SCAN) ? bsum[t] : 0;
    int inc = v;
    #pragma unroll
    for (int off = 1; off < 64; off <<= 1) {
        int u = __shfl_up(inc, off, 64);
        if (lane >= off) inc += u;
    }
    __shared__ int wsum[4];
    if (lane == 63) wsum[w] = inc;
    __syncthreads();
    int add = 0;
    for (int i = 0; i < w; ++i) add += wsum[i];
    if (t < NB_SCAN) boff[t] = add + inc - v;
}

// ---------------------------------------------------------------------------
// CSR scan phase C: local exclusive scan + boff, write rowptr and cursor.
// ---------------------------------------------------------------------------
__global__ __launch_bounds__(256) void scan_write_kernel(
        const int* __restrict__ boff, int* __restrict__ c,
        int* __restrict__ cursor) {
    const int t = threadIdx.x, lane = t & 63, w = t >> 6;
    const int i0 = blockIdx.x * 512 + 2 * t;
    int v0 = (i0     < N_DST) ? c[i0]     : 0;
    int v1 = (i0 + 1 < N_DST) ? c[i0 + 1] : 0;
    int s = v0 + v1;
    int inc = s;
    #pragma unroll
    for (int off = 1; off < 64; off <<= 1) {
        int u = __shfl_up(inc, off, 64);
        if (lane >= off) inc += u;
    }
    __shared__ int wsum[4];
    if (lane == 63) wsum[w] = inc;
    __syncthreads();
    int add = boff[blockIdx.x];
    for (int i = 0; i < w; ++i) add += wsum[i];
    int g = add + inc - s;                       // exclusive offset of i0
    if (i0 < N_DST)     { c[i0]     = g;      cursor[i0]     = g; }
    if (i0 + 1 < N_DST) { c[i0 + 1] = g + v0; cursor[i0 + 1] = g + v0; }
}

// ---------------------------------------------------------------------------
// CSR build, step 3: scatter (src, weight) pairs into dst-sorted order.
// ---------------------------------------------------------------------------
__global__ __launch_bounds__(256) void scatter_kernel(
        const int* __restrict__ src, const int* __restrict__ dst,
        const float* __restrict__ ew, int* __restrict__ cursor,
        int2* __restrict__ esw) {
    int i = blockIdx.x * blockDim.x + threadIdx.x;
    const int stride = gridDim.x * blockDim.x;
    for (; i < N_EDGES; i += stride) {
        int d   = dst[i];
        int pos = atomicAdd(&cursor[d], 1);
        esw[pos] = make_int2(src[i], __float_as_int(ew[i]));
    }
}

// ---------------------------------------------------------------------------
// Aggregate: one wave per dst row, no atomics; uniform CSR walk (scalar
// loads for esw/rp/cursor), coalesced 256B hs-row gathers.
// ---------------------------------------------------------------------------
__global__ __launch_bounds__(256) void aggregate_kernel(
        const float* __restrict__ hs, const int2* __restrict__ esw,
        const int* __restrict__ rp, const int* __restrict__ cursor,
        float* __restrict__ nv) {
    const int lane = threadIdx.x & 63;
    const int d = __builtin_amdgcn_readfirstlane(blockIdx.x * 4 + (threadIdx.x >> 6));
    if (d >= N_DST) return;
    int i = rp[d];
    const int e = cursor[d];
    float acc = 0.0f, ws = 0.0f;
    for (; i + 1 < e; i += 2) {
        int2 p0 = esw[i], p1 = esw[i + 1];
        float w0 = __int_as_float(p0.y), w1 = __int_as_float(p1.y);
        float h0 = hs[p0.x * 64 + lane];
        float h1 = hs[p1.x * 64 + lane];
        acc = fmaf(h0, w0, acc);
        acc = fmaf(h1, w1, acc);
        ws += w0 + w1;
    }
    if (i < e) {
        int2 p = esw[i];
        float w0 = __int_as_float(p.y);
        acc = fmaf(hs[p.x * 64 + lane], w0, acc);
        ws += w0;
    }
    nv[d * 64 + lane] = acc / fmaxf(ws, 1.0f);
}

// ---------------------------------------------------------------------------
// Kernel fc2 (restructured): new = relu(concat([nv, h_dst]) @ W2 + b2)
// 512-thread blocks, 8 waves = (col-half ch) x (k-quarter kq). Each wave
// holds wcol[32] — round-6 lesson: the allocator targets 8 waves/SIMD
// (<=64 VGPR) and spilled wcol[64] to scratch (VGPR_Count=48, 164us).
// 32 floats + __launch_bounds__(512,4) (cap 128 VGPR) cannot spill.
// x via scalar loads (uniform row & kq); 4-way partial combine in 16KB LDS.
// ---------------------------------------------------------------------------
__global__ __launch_bounds__(512, 4) void fc2_kernel(
        const float* __restrict__ nv, const float* __restrict__ h_dst,
        const float* __restrict__ W2, const float* __restrict__ b2,
        float* __restrict__ out, double* __restrict__ sumsq) {
    __shared__ float P[8 * 4 * 128];          // [row r][kq][col], 16 KiB
    const int lane = threadIdx.x & 63;
    const int wid  = threadIdx.x >> 6;        // 0..7
    const int ch   = wid & 1;                 // column half
    const int kq   = __builtin_amdgcn_readfirstlane(wid >> 1);   // k quarter 0..3
    const float* __restrict__ xsrc = (kq < 2) ? nv : h_dst;
    const int koff = (kq & 1) * 32;           // offset inside the 64-wide row

    float wcol[32];                           // W2[kq*32+kk][ch*64+lane]
    #pragma unroll
    for (int kk = 0; kk < 32; ++kk)
        wcol[kk] = W2[(kq * 32 + kk) * OUT_F + ch * 64 + lane];
    #pragma unroll
    for (int kk = 0; kk < 32; ++kk)
        asm volatile("" : "+v"(wcol[kk]));

    const float bias = b2[threadIdx.x & 127];
    double ss = 0.0;

    const int NG = N_DST / 8;                 // 12500 groups of 8 rows
    for (int g = blockIdx.x; g < NG; g += gridDim.x) {
        const int base = g * 8;
        #pragma unroll
        for (int r = 0; r < 8; ++r) {
            const float* __restrict__ xr = xsrc + (size_t)(base + r) * 64 + koff;
            float a0 = 0.f, a1 = 0.f, a2 = 0.f, a3 = 0.f;
            #pragma unroll
            for (int kk = 0; kk < 32; kk += 4) {
                a0 = fmaf(xr[kk],     wcol[kk],     a0);   // s_load broadcast
                a1 = fmaf(xr[kk + 1], wcol[kk + 1], a1);
                a2 = fmaf(xr[kk + 2], wcol[kk + 2], a2);
                a3 = fmaf(xr[kk + 3], wcol[kk + 3], a3);
            }
            P[r * 512 + kq * 128 + ch * 64 + lane] = (a0 + a1) + (a2 + a3);
        }
        __syncthreads();
        #pragma unroll
        for (int v = 0; v < 2; ++v) {
            int idx = v * 512 + (int)threadIdx.x;
            int row = idx >> 7, col = idx & 127;
            const float* Pr = P + row * 512;
            float s = Pr[col] + Pr[128 + col] + Pr[256 + col] + Pr[384 + col] + bias;
            float val = fmaxf(s, 0.0f);
            out[(base + row) * OUT_F + col] = val;
            ss += (double)val * (double)val;
        }
        __syncthreads();                      // WAR: P overwritten next round
    }
    #pragma unroll
    for (int off = 32; off > 0; off >>= 1) ss += __shfl_down(ss, off, 64);
    if (lane == 0) atomicAdd(sumsq, ss);
}

// ---------------------------------------------------------------------------
// Kernel: out *= 1/sqrt(sumsq)   (in-place, float4 grid-stride)
// ---------------------------------------------------------------------------
__global__ __launch_bounds__(256) void scale_kernel(
        float* __restrict__ out, const double* __restrict__ sumsq, int n4) {
    const float s = (float)(1.0 / sqrt(*sumsq));
    float4* o4 = (float4*)out;
    const int stride = gridDim.x * blockDim.x;
    for (int i = blockIdx.x * blockDim.x + threadIdx.x; i < n4; i += stride) {
        float4 v = o4[i];
        v.x *= s; v.y *= s; v.z *= s; v.w *= s;
        o4[i] = v;
    }
}

extern "C" void kernel_launch(void* const* d_in, const int* in_sizes, int n_in,
                              void* d_out, int out_size, void* d_ws, size_t ws_size,
                              hipStream_t stream) {
    const float* h_src = (const float*)d_in[0];
    const float* h_dst = (const float*)d_in[1];
    const float* ew    = (const float*)d_in[2];
    const float* W1    = (const float*)d_in[3];
    const float* b1    = (const float*)d_in[4];
    const float* W2    = (const float*)d_in[5];
    const float* b2    = (const float*)d_in[6];
    const int*   src   = (const int*)d_in[7];
    const int*   dst   = (const int*)d_in[8];
    float* out = (float*)d_out;

    // d_out (51.2 MB) doubles as scratch before fc2 rewrites it entirely:
    //   [0       , 25.6 MB) : hs               (dead after aggregate)
    //   [25.6 MB , 35.6 MB) : esw  int2[1.25M] (dead after aggregate)
    //   [35.6 MB , 36.0 MB) : rowptrA int[100k]  counts -> rowptr in place
    //   [36.0 MB , 36.4 MB) : cursor  int[100k]
    //   [36.4 MB , +~1 KB ) : bsum[196], boff[196]
    // d_ws:
    //   [0       , 25.6 MB) : nv   (live through fc2)
    //   [25.6 MB , +8 B   ) : sumsq
    float* hs      = out;
    int2*  esw     = (int2*)((char*)d_out + 25600000);
    int*   rowptrA = (int*)((char*)d_out + 35600000);
    int*   cursor  = (int*)((char*)d_out + 36000000);
    int*   bsum    = (int*)((char*)d_out + 36400000);
    int*   boff    = bsum + 256;
    float* nv      = (float*)d_ws;
    double* sumsq  = (double*)((char*)d_ws + 25600000);

    hipMemsetAsync(rowptrA, 0, (size_t)N_DST * 4, stream);
    hipMemsetAsync(sumsq, 0, 8, stream);

    fc1_kernel<<<2048, 256, 0, stream>>>(h_src, W1, b1, hs);
    hist_kernel<<<1024, 256, 0, stream>>>(dst, rowptrA);
    scan_bsum_kernel<<<NB_SCAN, 256, 0, stream>>>(rowptrA, bsum);
    scan_boff_kernel<<<1, 256, 0, stream>>>(bsum, boff);
    scan_write_kernel<<<NB_SCAN, 256, 0, stream>>>(boff, rowptrA, cursor);
    scatter_kernel<<<1024, 256, 0, stream>>>(src, dst, ew, cursor, esw);
    aggregate_kernel<<<(N_DST + 3) / 4, 256, 0, stream>>>(hs, esw, rowptrA, cursor, nv);
    fc2_kernel<<<1024, 512, 0, stream>>>(nv, h_dst, W2, b2, out, sumsq);
    scale_kernel<<<2048, 256, 0, stream>>>(out, sumsq, N_DST * OUT_F / 4);
}

// Round 8
// 403.989 us; speedup vs baseline: 1.0195x; 1.0195x over previous
//
#include <hip/hip_runtime.h>

#define N_SRC   100000
#define N_DST   100000
#define N_EDGES 1250000
#define D_FEAT  64
#define HIDDEN  64
#define OUT_F   128

#define NB_SCAN 196   // ceil(N_DST / 512); each scan block owns 512 counts

// ---------------------------------------------------------------------------
// Kernel 1: hs = relu(h_src @ W1 + b1)   [N_SRC, 64]
// Wave per 8-row group. NO persistent weight array (rounds 4-7 lesson: the
// allocator spills any long-lived per-lane array). Instead: k-chunks of 8 —
// load 8 weights (coalesced, L1-resident), apply to 8 rows (64 FMA), move on.
// Live set ~30 VGPR. x via scalar loads (uniform row) -> SGPR broadcast.
// ---------------------------------------------------------------------------
__global__ __launch_bounds__(256) void fc1_kernel(
        const float* __restrict__ h_src, const float* __restrict__ W1,
        const float* __restrict__ b1, float* __restrict__ hs) {
    const int lane = threadIdx.x & 63;
    const float bias = b1[lane];
    const int wid    = blockIdx.x * 4 + (threadIdx.x >> 6);
    const int stride = gridDim.x * 4;
    const int NG = N_SRC / 8;                  // 12500 groups of 8 rows
    for (int g = wid; g < NG; g += stride) {
        const int base = __builtin_amdgcn_readfirstlane(g) * 8;
        float acc[8];
        #pragma unroll
        for (int r = 0; r < 8; ++r) acc[r] = bias;
        #pragma unroll
        for (int c = 0; c < 8; ++c) {          // 8 k-chunks of 8
            float w[8];
            #pragma unroll
            for (int j = 0; j < 8; ++j)
                w[j] = W1[(c * 8 + j) * HIDDEN + lane];
            #pragma unroll
            for (int r = 0; r < 8; ++r) {
                const float* __restrict__ xr = h_src + (size_t)(base + r) * 64 + c * 8;
                #pragma unroll
                for (int j = 0; j < 8; ++j)
                    acc[r] = fmaf(xr[j], w[j], acc[r]);   // xr[j]: s_load
            }
        }
        #pragma unroll
        for (int r = 0; r < 8; ++r)
            hs[(size_t)(base + r) * 64 + lane] = fmaxf(acc[r], 0.0f);
    }
}

// ---------------------------------------------------------------------------
// CSR build, step 1: histogram of dst.
// ---------------------------------------------------------------------------
__global__ __launch_bounds__(256) void hist_kernel(
        const int* __restrict__ dst, int* __restrict__ counts) {
    int i = blockIdx.x * blockDim.x + threadIdx.x;
    const int stride = gridDim.x * blockDim.x;
    for (; i < N_EDGES; i += stride) atomicAdd(&counts[dst[i]], 1);
}

// ---------------------------------------------------------------------------
// CSR scan phase A: per-block sums (196 blocks x 512 counts).
// ---------------------------------------------------------------------------
__global__ __launch_bounds__(256) void scan_bsum_kernel(
        const int* __restrict__ c, int* __restrict__ bsum) {
    const int t  = threadIdx.x;
    const int i0 = blockIdx.x * 512 + 2 * t;
    int v0 = (i0     < N_DST) ? c[i0]     : 0;
    int v1 = (i0 + 1 < N_DST) ? c[i0 + 1] : 0;
    int s = v0 + v1;
    #pragma unroll
    for (int off = 32; off > 0; off >>= 1) s += __shfl_down(s, off, 64);
    __shared__ int ws[4];
    if ((t & 63) == 0) ws[t >> 6] = s;
    __syncthreads();
    if (t == 0) bsum[blockIdx.x] = ws[0] + ws[1] + ws[2] + ws[3];
}

// ---------------------------------------------------------------------------
// CSR scan phase B: single small block — exclusive scan of the 196 sums.
// ---------------------------------------------------------------------------
__global__ __launch_bounds__(256) void scan_boff_kernel(
        const int* __restrict__ bsum, int* __restrict__ boff) {
    const int t = threadIdx.x, lane = t & 63, w = t >> 6;
    int v = (t < NB_SCAN) ? bsum[t] : 0;
    int inc = v;
    #pragma unroll
    for (int off = 1; off < 64; off <<= 1) {
        int u = __shfl_up(inc, off, 64);
        if (lane >= off) inc += u;
    }
    __shared__ int wsum[4];
    if (lane == 63) wsum[w] = inc;
    __syncthreads();
    int add = 0;
    for (int i = 0; i < w; ++i) add += wsum[i];
    if (t < NB_SCAN) boff[t] = add + inc - v;
}

// ---------------------------------------------------------------------------
// CSR scan phase C: local exclusive scan + boff, write rowptr and cursor.
// ---------------------------------------------------------------------------
__global__ __launch_bounds__(256) void scan_write_kernel(
        const int* __restrict__ boff, int* __restrict__ c,
        int* __restrict__ cursor) {
    const int t = threadIdx.x, lane = t & 63, w = t >> 6;
    const int i0 = blockIdx.x * 512 + 2 * t;
    int v0 = (i0     < N_DST) ? c[i0]     : 0;
    int v1 = (i0 + 1 < N_DST) ? c[i0 + 1] : 0;
    int s = v0 + v1;
    int inc = s;
    #pragma unroll
    for (int off = 1; off < 64; off <<= 1) {
        int u = __shfl_up(inc, off, 64);
        if (lane >= off) inc += u;
    }
    __shared__ int wsum[4];
    if (lane == 63) wsum[w] = inc;
    __syncthreads();
    int add = boff[blockIdx.x];
    for (int i = 0; i < w; ++i) add += wsum[i];
    int g = add + inc - s;                       // exclusive offset of i0
    if (i0 < N_DST)     { c[i0]     = g;      cursor[i0]     = g; }
    if (i0 + 1 < N_DST) { c[i0 + 1] = g + v0; cursor[i0 + 1] = g + v0; }
}

// ---------------------------------------------------------------------------
// CSR build, step 3: scatter (src, weight) pairs into dst-sorted order.
// ---------------------------------------------------------------------------
__global__ __launch_bounds__(256) void scatter_kernel(
        const int* __restrict__ src, const int* __restrict__ dst,
        const float* __restrict__ ew, int* __restrict__ cursor,
        int2* __restrict__ esw) {
    int i = blockIdx.x * blockDim.x + threadIdx.x;
    const int stride = gridDim.x * blockDim.x;
    for (; i < N_EDGES; i += stride) {
        int d   = dst[i];
        int pos = atomicAdd(&cursor[d], 1);
        esw[pos] = make_int2(src[i], __float_as_int(ew[i]));
    }
}

// ---------------------------------------------------------------------------
// Aggregate: one wave per dst row, no atomics; uniform CSR walk (scalar
// loads for esw/rp/cursor), coalesced 256B hs-row gathers.
// ---------------------------------------------------------------------------
__global__ __launch_bounds__(256) void aggregate_kernel(
        const float* __restrict__ hs, const int2* __restrict__ esw,
        const int* __restrict__ rp, const int* __restrict__ cursor,
        float* __restrict__ nv) {
    const int lane = threadIdx.x & 63;
    const int d = __builtin_amdgcn_readfirstlane(blockIdx.x * 4 + (threadIdx.x >> 6));
    if (d >= N_DST) return;
    int i = rp[d];
    const int e = cursor[d];
    float acc = 0.0f, ws = 0.0f;
    for (; i + 1 < e; i += 2) {
        int2 p0 = esw[i], p1 = esw[i + 1];
        float w0 = __int_as_float(p0.y), w1 = __int_as_float(p1.y);
        float h0 = hs[p0.x * 64 + lane];
        float h1 = hs[p1.x * 64 + lane];
        acc = fmaf(h0, w0, acc);
        acc = fmaf(h1, w1, acc);
        ws += w0 + w1;
    }
    if (i < e) {
        int2 p = esw[i];
        float w0 = __int_as_float(p.y);
        acc = fmaf(hs[p.x * 64 + lane], w0, acc);
        ws += w0;
    }
    nv[d * 64 + lane] = acc / fmaxf(ws, 1.0f);
}

// ---------------------------------------------------------------------------
// Kernel fc2: new = relu(concat([nv, h_dst]) @ W2 + b2)
// 256-thread (ch, kh) wave split as round 5, but NO persistent wcol array:
// k-chunks of 8 weights, reused across the 8-row group (8:1 FMA:load, W2
// L1/L2-resident). Live set ~30 VGPR -> nothing to spill at any occupancy.
// x via scalar loads; partials combined through 8 KB LDS.
// ---------------------------------------------------------------------------
__global__ __launch_bounds__(256) void fc2_kernel(
        const float* __restrict__ nv, const float* __restrict__ h_dst,
        const float* __restrict__ W2, const float* __restrict__ b2,
        float* __restrict__ out, double* __restrict__ sumsq) {
    __shared__ float P[8 * 2 * 128];          // [row r][k-half][col], 8 KiB
    const int lane = threadIdx.x & 63;
    const int wid  = threadIdx.x >> 6;
    const int ch   = wid & 1;                 // column half
    const int khu  = __builtin_amdgcn_readfirstlane(wid >> 1);  // k half
    const float* __restrict__ xsrc = khu ? h_dst : nv;
    const float* __restrict__ wsrc = W2 + (size_t)khu * 64 * OUT_F + ch * 64 + lane;

    const float bias = b2[threadIdx.x & 127];
    double ss = 0.0;

    const int NG = N_DST / 8;                 // 12500 groups of 8 rows
    for (int g = blockIdx.x; g < NG; g += gridDim.x) {
        const int base = g * 8;
        float acc[8];
        #pragma unroll
        for (int r = 0; r < 8; ++r) acc[r] = 0.0f;
        #pragma unroll
        for (int c = 0; c < 8; ++c) {          // 8 k-chunks of 8 (k-half = 64)
            float w[8];
            #pragma unroll
            for (int j = 0; j < 8; ++j)
                w[j] = wsrc[(size_t)(c * 8 + j) * OUT_F];
            #pragma unroll
            for (int r = 0; r < 8; ++r) {
                const float* __restrict__ xr = xsrc + (size_t)(base + r) * 64 + c * 8;
                #pragma unroll
                for (int j = 0; j < 8; ++j)
                    acc[r] = fmaf(xr[j], w[j], acc[r]);   // xr[j]: s_load
            }
        }
        #pragma unroll
        for (int r = 0; r < 8; ++r)
            P[r * 256 + khu * 128 + ch * 64 + lane] = acc[r];
        __syncthreads();
        #pragma unroll
        for (int v = 0; v < 4; ++v) {
            int idx = v * 256 + (int)threadIdx.x;
            int row = idx >> 7, col = idx & 127;
            float s = P[row * 256 + col] + P[row * 256 + 128 + col] + bias;
            float val = fmaxf(s, 0.0f);
            out[(base + row) * OUT_F + col] = val;
            ss += (double)val * (double)val;
        }
        __syncthreads();                      // WAR: P overwritten next round
    }
    #pragma unroll
    for (int off = 32; off > 0; off >>= 1) ss += __shfl_down(ss, off, 64);
    if (lane == 0) atomicAdd(sumsq, ss);
}

// ---------------------------------------------------------------------------
// Kernel: out *= 1/sqrt(sumsq)   (in-place, float4 grid-stride)
// ---------------------------------------------------------------------------
__global__ __launch_bounds__(256) void scale_kernel(
        float* __restrict__ out, const double* __restrict__ sumsq, int n4) {
    const float s = (float)(1.0 / sqrt(*sumsq));
    float4* o4 = (float4*)out;
    const int stride = gridDim.x * blockDim.x;
    for (int i = blockIdx.x * blockDim.x + threadIdx.x; i < n4; i += stride) {
        float4 v = o4[i];
        v.x *= s; v.y *= s; v.z *= s; v.w *= s;
        o4[i] = v;
    }
}

extern "C" void kernel_launch(void* const* d_in, const int* in_sizes, int n_in,
                              void* d_out, int out_size, void* d_ws, size_t ws_size,
                              hipStream_t stream) {
    const float* h_src = (const float*)d_in[0];
    const float* h_dst = (const float*)d_in[1];
    const float* ew    = (const float*)d_in[2];
    const float* W1    = (const float*)d_in[3];
    const float* b1    = (const float*)d_in[4];
    const float* W2    = (const float*)d_in[5];
    const float* b2    = (const float*)d_in[6];
    const int*   src   = (const int*)d_in[7];
    const int*   dst   = (const int*)d_in[8];
    float* out = (float*)d_out;

    // d_out (51.2 MB) doubles as scratch before fc2 rewrites it entirely:
    //   [0       , 25.6 MB) : hs               (dead after aggregate)
    //   [25.6 MB , 35.6 MB) : esw  int2[1.25M] (dead after aggregate)
    //   [35.6 MB , 36.0 MB) : rowptrA int[100k]  counts -> rowptr in place
    //   [36.0 MB , 36.4 MB) : cursor  int[100k]
    //   [36.4 MB , +~1 KB ) : bsum[196], boff[196]
    // d_ws:
    //   [0       , 25.6 MB) : nv   (live through fc2)
    //   [25.6 MB , +8 B   ) : sumsq
    float* hs      = out;
    int2*  esw     = (int2*)((char*)d_out + 25600000);
    int*   rowptrA = (int*)((char*)d_out + 35600000);
    int*   cursor  = (int*)((char*)d_out + 36000000);
    int*   bsum    = (int*)((char*)d_out + 36400000);
    int*   boff    = bsum + 256;
    float* nv      = (float*)d_ws;
    double* sumsq  = (double*)((char*)d_ws + 25600000);

    hipMemsetAsync(rowptrA, 0, (size_t)N_DST * 4, stream);
    hipMemsetAsync(sumsq, 0, 8, stream);

    fc1_kernel<<<2048, 256, 0, stream>>>(h_src, W1, b1, hs);
    hist_kernel<<<1024, 256, 0, stream>>>(dst, rowptrA);
    scan_bsum_kernel<<<NB_SCAN, 256, 0, stream>>>(rowptrA, bsum);
    scan_boff_kernel<<<1, 256, 0, stream>>>(bsum, boff);
    scan_write_kernel<<<NB_SCAN, 256, 0, stream>>>(boff, rowptrA, cursor);
    scatter_kernel<<<1024, 256, 0, stream>>>(src, dst, ew, cursor, esw);
    aggregate_kernel<<<(N_DST + 3) / 4, 256, 0, stream>>>(hs, esw, rowptrA, cursor, nv);
    fc2_kernel<<<2048, 256, 0, stream>>>(nv, h_dst, W2, b2, out, sumsq);
    scale_kernel<<<2048, 256, 0, stream>>>(out, sumsq, N_DST * OUT_F / 4);
}